// Round 16
// baseline (13.535 us; speedup 1.0000x reference)
//
#include <hip/hip_runtime.h>
#include <hip/hip_fp16.h>

// ComplexMixture: B=32, S=128, N=256
// Or[b,n,m] = sum_s w[b,s]*(r[b,s,n]*r[b,s,m] + i[b,s,n]*i[b,s,m])
// Oi[b,n,m] = sum_s w[b,s]*(i[b,s,n]*r[b,s,m] - r[b,s,n]*i[b,s,m])
//
// R16 = R9 geometry (single 64x64 tile/block, 64 KB LDS, 512 blocks =
// 2 blocks/CU -> cross-block store-tail overlap) + R12's counted lgkm-only
// barriers (H1 prefetch loads genuinely fly under MFMA-H0; R9's
// __syncthreads was draining them with vmcnt(0)).
// K-half pipeline: load H0 -> cvt/write H0 -> issue H1 loads -> LBAR ->
// MFMA ks0-1 (H1 in flight) -> cvt/write H1 (slots disjoint via bit 3) ->
// LBAR -> MFMA ks2-3 with ms-split stores.
// Swizzle slot = chunk ^ ((row>>1)&7): conflict-free b128 writes, 2-way
// (free) b128 reads. setprio around MFMA. XCD-grouped bid swizzle.

constexpr int B = 32, S = 128, N = 256;

typedef _Float16 f16x8 __attribute__((ext_vector_type(8)));
typedef float    f32x4 __attribute__((ext_vector_type(4)));

union F16x8 { f16x8 v; __half2 h2[4]; };

#define MFMA16(a, bv, c) __builtin_amdgcn_mfma_f32_16x16x32_f16((a), (bv), (c), 0, 0, 0)

// LDS-only barrier: waits this thread's ds ops, NOT vmem (loads/stores fly).
#define LBAR() {                                                             \
        __builtin_amdgcn_sched_barrier(0);                                   \
        asm volatile("s_waitcnt lgkmcnt(0)" ::: "memory");                   \
        __builtin_amdgcn_s_barrier();                                        \
        __builtin_amdgcn_sched_barrier(0); }

__global__ __launch_bounds__(512, 4) void ComplexMixture_71313636983193_kernel(
    const float* __restrict__ R, const float* __restrict__ I,
    const float* __restrict__ W, float* __restrict__ Or, float* __restrict__ Oi)
{
    // T[0]=w*r (A rows), T[1]=w*i, T[2]=r (B rows), T[3]=i
    // row n, logical chunk c (8 s) at slot c ^ ((n>>1)&7)
    __shared__ alignas(16) _Float16 T[4][64][128];   // 64 KB

    const int pb   = blockIdx.x;
    const int lbid = (pb & 7) * 64 + (pb >> 3);   // batch-group per XCD
    const int b  = lbid >> 4;
    const int ti = (lbid >> 2) & 3;               // A-side n-chunk
    const int tj = lbid & 3;                      // B-side m-chunk
    const int t  = threadIdx.x;
    const int wv = t >> 6, lane = t & 63;

    // staging task: 512 = nquad(16) x octet(8) x side(2) x arr(2)
    const int nquad = t & 15;          // n = nquad*4 + j
    const int octet = (t >> 4) & 7;    // s-octet within K-half
    const int side  = (t >> 7) & 1;    // 0 = A(ti), 1 = B(tj)  (wave-uniform)
    const int arr   = t >> 8;          // 0 = real, 1 = imag    (wave-uniform)

    const size_t bb = (size_t)b * S * N;
    const int chunk = side ? tj : ti;
    const float* src = (arr ? I : R) + bb + chunk * 64 + nquad * 4;
    const float* Wb  = W + b * S;

    _Float16 (* const Td)[128] = T[side * 2 + arr];

    // ---- issue H0 loads (s = octet*8 + 0..7) ----
    float4 f0[8];
    #pragma unroll
    for (int s = 0; s < 8; ++s)
        f0[s] = *(const float4*)&src[(size_t)(octet * 8 + s) * N];

    float w0[8], w1[8];
    if (side == 0) {
        const float4 a0 = *(const float4*)&Wb[octet * 8];
        const float4 a1 = *(const float4*)&Wb[octet * 8 + 4];
        const float4 a2 = *(const float4*)&Wb[64 + octet * 8];
        const float4 a3 = *(const float4*)&Wb[64 + octet * 8 + 4];
        w0[0]=a0.x; w0[1]=a0.y; w0[2]=a0.z; w0[3]=a0.w;
        w0[4]=a1.x; w0[5]=a1.y; w0[6]=a1.z; w0[7]=a1.w;
        w1[0]=a2.x; w1[1]=a2.y; w1[2]=a2.z; w1[3]=a2.w;
        w1[4]=a3.x; w1[5]=a3.y; w1[6]=a3.z; w1[7]=a3.w;
    }

    // ---- convert + write H0 (chunk c = octet) ----
    #pragma unroll
    for (int j = 0; j < 4; ++j) {
        const int n    = nquad * 4 + j;
        const int slot = octet ^ ((n >> 1) & 7);
        F16x8 f;
        #pragma unroll
        for (int k = 0; k < 4; ++k) {
            float lo = ((const float*)&f0[2 * k])[j];
            float hi = ((const float*)&f0[2 * k + 1])[j];
            if (side == 0) { lo *= w0[2 * k]; hi *= w0[2 * k + 1]; }
            f.h2[k] = __floats2half2_rn(lo, hi);
        }
        *(f16x8*)&Td[n][slot * 8] = f.v;
    }

    // ---- issue H1 loads; they genuinely fly under MFMA-H0 (LBAR) ----
    float4 f1[8];
    #pragma unroll
    for (int s = 0; s < 8; ++s)
        f1[s] = *(const float4*)&src[(size_t)(64 + octet * 8 + s) * N];

    LBAR();   // H0 tiles visible; H1 loads still in flight

    // ---- MFMA geometry: wave = 16(n) x 32(m) sub-tile ----
    const int wn = (wv & 3) * 16;
    const int wm = (wv >> 2) * 32;
    const int fr16 = lane & 15, kb = lane >> 4;
    const int ra  = wn + fr16;          const int sa  = (ra  >> 1) & 7;
    const int rb0 = wm + fr16;          const int sb0 = (rb0 >> 1) & 7;
    const int rb1 = wm + 16 + fr16;     const int sb1 = (rb1 >> 1) & 7;

    f32x4 accR[2] = {}, accA[2] = {}, accB[2] = {};
    f16x8 awr, awi;

#define LOAD_A(ks) { const int ca = (((ks) * 4 + kb) ^ sa) * 8;              \
        awr = *(const f16x8*)&T[0][ra][ca];                                  \
        awi = *(const f16x8*)&T[1][ra][ca]; }
#define STEP_B(ks, ms) { const int K = (ks) * 4 + kb;                        \
        const int rb = (ms) ? rb1 : rb0;                                     \
        const int cb = (K ^ ((ms) ? sb1 : sb0)) * 8;                         \
        const f16x8 br = *(const f16x8*)&T[2][rb][cb];                       \
        const f16x8 bi = *(const f16x8*)&T[3][rb][cb];                       \
        accR[ms] = MFMA16(awr, br, accR[ms]);                                \
        accR[ms] = MFMA16(awi, bi, accR[ms]);                                \
        accA[ms] = MFMA16(awi, br, accA[ms]);                                \
        accB[ms] = MFMA16(awr, bi, accB[ms]); }

    // ---- MFMA over H0 (ks = 0,1), H1 loads draining underneath ----
    __builtin_amdgcn_s_setprio(1);
    LOAD_A(0); STEP_B(0, 0); STEP_B(0, 1);
    LOAD_A(1); STEP_B(1, 0); STEP_B(1, 1);
    __builtin_amdgcn_s_setprio(0);

    // ---- convert + write H1 (chunk c = 8+octet; slots disjoint via bit 3) --
    #pragma unroll
    for (int j = 0; j < 4; ++j) {
        const int n    = nquad * 4 + j;
        const int slot = (8 + octet) ^ ((n >> 1) & 7);
        F16x8 f;
        #pragma unroll
        for (int k = 0; k < 4; ++k) {
            float lo = ((const float*)&f1[2 * k])[j];
            float hi = ((const float*)&f1[2 * k + 1])[j];
            if (side == 0) { lo *= w1[2 * k]; hi *= w1[2 * k + 1]; }
            f.h2[k] = __floats2half2_rn(lo, hi);
        }
        *(f16x8*)&Td[n][slot * 8] = f.v;
    }

    LBAR();   // H1 tiles visible

    const int n0 = ti * 64, m0 = tj * 64;
    const int nn = n0 + wn + kb * 4;

#define STORE_MS(ms) {                                                       \
        const int mm = m0 + wm + (ms) * 16 + fr16;                           \
        _Pragma("unroll")                                                    \
        for (int r = 0; r < 4; ++r) {                                        \
            const size_t o = ((size_t)b * N + nn + r) * N + mm;              \
            Or[o] = accR[ms][r];                                             \
            Oi[o] = accA[ms][r] - accB[ms][r];                               \
        } }

    // ---- MFMA over H1 (ks = 2,3) with ms-split stores ----
    __builtin_amdgcn_s_setprio(1);
    LOAD_A(2); STEP_B(2, 0); STEP_B(2, 1);
    LOAD_A(3); STEP_B(3, 0);
    __builtin_amdgcn_s_setprio(0);
    STORE_MS(0);                 // HBM drain starts while ms=1 finishes
    __builtin_amdgcn_s_setprio(1);
    STEP_B(3, 1);
    __builtin_amdgcn_s_setprio(0);
    STORE_MS(1);
}

extern "C" void kernel_launch(void* const* d_in, const int* in_sizes, int n_in,
                              void* d_out, int out_size, void* d_ws, size_t ws_size,
                              hipStream_t stream) {
    const float* R = (const float*)d_in[0];
    const float* I = (const float*)d_in[1];
    const float* W = (const float*)d_in[2];
    float* Or = (float*)d_out;
    float* Oi = (float*)d_out + (size_t)B * N * N;

    ComplexMixture_71313636983193_kernel<<<dim3(512), dim3(512), 0, stream>>>(
        R, I, W, Or, Oi);
}

// Round 17
// 12.832 us; speedup vs baseline: 1.0548x; 1.0548x over previous
//
#include <hip/hip_runtime.h>
#include <hip/hip_fp16.h>

// ComplexMixture: B=32, S=128, N=256
// Or[b,n,m] = sum_s w[b,s]*(r[b,s,n]*r[b,s,m] + i[b,s,n]*i[b,s,m])
// Oi[b,n,m] = sum_s w[b,s]*(i[b,s,n]*r[b,s,m] - r[b,s,n]*i[b,s,m])
//
// FINAL (= R12, best of 16 rounds at 12.62 µs): single fused kernel.
// 256 blocks x 512 threads; block computes tiles (ti,tj1),(ti,tj2) of one
// batch sharing the weighted A-side. Counted lgkm-only barriers (T4): B2
// prefetch loads and tile-1 stores stay in flight across barriers.
// f16 16x16x32 MFMA; swizzle slot = chunk ^ ((row>>1)&7) (conflict-free
// b128 staging writes, free 2-way fragment reads); ms-split tail stores;
// setprio around MFMA; XCD-grouped bid swizzle. LDS 96 KB.
// Measured-and-rejected: 32x32 MFMA (VGPR blowup R13/R14), A-frag reg
// cache (R15), 2 blk/CU single-tile (R16), cross-block ws handshake (R4).

constexpr int B = 32, S = 128, N = 256;

typedef _Float16 f16x8 __attribute__((ext_vector_type(8)));
typedef float    f32x4 __attribute__((ext_vector_type(4)));

union F16x8 { f16x8 v; __half2 h2[4]; };

#define MFMA16(a, bv, c) __builtin_amdgcn_mfma_f32_16x16x32_f16((a), (bv), (c), 0, 0, 0)

// LDS-only barrier: waits this thread's ds ops, NOT vmem (loads/stores fly).
#define LBAR() {                                                             \
        __builtin_amdgcn_sched_barrier(0);                                   \
        asm volatile("s_waitcnt lgkmcnt(0)" ::: "memory");                   \
        __builtin_amdgcn_s_barrier();                                        \
        __builtin_amdgcn_sched_barrier(0); }

__global__ __launch_bounds__(512, 2) void ComplexMixture_71313636983193_kernel(
    const float* __restrict__ R, const float* __restrict__ I,
    const float* __restrict__ W, float* __restrict__ Or, float* __restrict__ Oi)
{
    // T[0..1] = w*r, w*i (A rows = n-chunk ti)
    // T[2..3] = r, i (B rows = m-chunk tj1);  T[4..5] = r, i (m-chunk tj2)
    // row x, logical chunk c (8 s) at slot c ^ ((x>>1)&7)
    __shared__ alignas(16) _Float16 T[6][64][128];   // 96 KB

    const int pb   = blockIdx.x;
    const int lbid = (pb & 7) * 32 + (pb >> 3);   // 4 batches per XCD
    const int b   = lbid >> 3;
    const int rem = lbid & 7;
    const int ti  = rem >> 1;          // A-side n-chunk
    const int uu  = rem & 1;
    const int tj1 = uu * 2, tj2 = uu * 2 + 1;   // the two B-side m-chunks

    const int t  = threadIdx.x;
    const int wv = t >> 6, lane = t & 63;

    // staging task: 512 = nquad(16) x octet(16) x arr(2)
    const int nquad = t & 15;          // n = nquad*4 + j
    const int octet = (t >> 4) & 15;   // s-octet 0..15 (full K)
    const int arr   = t >> 8;          // 0 = real, 1 = imag (wave-uniform)
    const int s0    = octet * 8;

    const size_t bb = (size_t)b * S * N;
    const float* base  = (arr ? I : R) + bb + nquad * 4;
    const float* srcA  = base + ti  * 64;
    const float* srcB1 = base + tj1 * 64;
    const float* srcB2 = base + tj2 * 64;
    const float* Wb = W + b * S;

    // ---- issue A + B1 loads (8 rows of 4 n each) ----
    float4 fA[8], fB1[8];
    #pragma unroll
    for (int s = 0; s < 8; ++s)
        fA[s] = *(const float4*)&srcA[(size_t)(s0 + s) * N];
    #pragma unroll
    for (int s = 0; s < 8; ++s)
        fB1[s] = *(const float4*)&srcB1[(size_t)(s0 + s) * N];

    float w8[8];
    {
        const float4 a0 = *(const float4*)&Wb[s0];
        const float4 a1 = *(const float4*)&Wb[s0 + 4];
        w8[0]=a0.x; w8[1]=a0.y; w8[2]=a0.z; w8[3]=a0.w;
        w8[4]=a1.x; w8[5]=a1.y; w8[6]=a1.z; w8[7]=a1.w;
    }

    // ---- cvt + write A (weighted) and B1 ----
    #pragma unroll
    for (int j = 0; j < 4; ++j) {
        const int n    = nquad * 4 + j;
        const int slot = octet ^ ((n >> 1) & 7);
        F16x8 fa, fb;
        #pragma unroll
        for (int k = 0; k < 4; ++k) {
            fa.h2[k] = __floats2half2_rn(((const float*)&fA[2*k])[j]   * w8[2*k],
                                         ((const float*)&fA[2*k+1])[j] * w8[2*k+1]);
            fb.h2[k] = __floats2half2_rn(((const float*)&fB1[2*k])[j],
                                         ((const float*)&fB1[2*k+1])[j]);
        }
        *(f16x8*)&T[arr][n][slot * 8]     = fa.v;
        *(f16x8*)&T[2 + arr][n][slot * 8] = fb.v;
    }

    // ---- issue B2 loads; they fly across the (lgkm-only) barrier ----
    float4 fB2[8];
    #pragma unroll
    for (int s = 0; s < 8; ++s)
        fB2[s] = *(const float4*)&srcB2[(size_t)(s0 + s) * N];

    LBAR();   // A, B1 visible; B2 loads still in flight

    // ---- MFMA geometry (R9-proven): wave = 16(n) x 32(m) sub-tile ----
    const int wn = (wv & 3) * 16;
    const int wm = (wv >> 2) * 32;
    const int fr16 = lane & 15, kb = lane >> 4;
    const int ra  = wn + fr16;          const int sa  = (ra  >> 1) & 7;
    const int rb0 = wm + fr16;          const int sb0 = (rb0 >> 1) & 7;
    const int rb1 = wm + 16 + fr16;     const int sb1 = (rb1 >> 1) & 7;

    f16x8 awr, awi;

#define LOAD_A(ks) { const int ca = (((ks) * 4 + kb) ^ sa) * 8;              \
        awr = *(const f16x8*)&T[0][ra][ca];                                  \
        awi = *(const f16x8*)&T[1][ra][ca]; }
#define STEP_B(TB, ks, ms, aR, aA, aB) { const int K = (ks) * 4 + kb;        \
        const int rb = (ms) ? rb1 : rb0;                                     \
        const int cb = (K ^ ((ms) ? sb1 : sb0)) * 8;                         \
        const f16x8 br = *(const f16x8*)&T[TB][rb][cb];                      \
        const f16x8 bi = *(const f16x8*)&T[(TB) + 1][rb][cb];                \
        aR[ms] = MFMA16(awr, br, aR[ms]);                                    \
        aR[ms] = MFMA16(awi, bi, aR[ms]);                                    \
        aA[ms] = MFMA16(awi, br, aA[ms]);                                    \
        aB[ms] = MFMA16(awr, bi, aB[ms]); }

    const int n0 = ti * 64;
    const int nn = n0 + wn + kb * 4;

#define STORE_MS(TJ, ms, aR, aA, aB) {                                       \
        const int mm = (TJ) * 64 + wm + (ms) * 16 + fr16;                    \
        _Pragma("unroll")                                                    \
        for (int r = 0; r < 4; ++r) {                                        \
            const size_t o = ((size_t)b * N + nn + r) * N + mm;              \
            Or[o] = aR[ms][r];                                               \
            Oi[o] = aA[ms][r] - aB[ms][r];                                   \
        } }

#define B2CVT(j) {                                                           \
        const int n    = nquad * 4 + (j);                                    \
        const int slot = octet ^ ((n >> 1) & 7);                             \
        F16x8 fb;                                                            \
        _Pragma("unroll")                                                    \
        for (int k = 0; k < 4; ++k)                                          \
            fb.h2[k] = __floats2half2_rn(((const float*)&fB2[2*k])[(j)],     \
                                         ((const float*)&fB2[2*k+1])[(j)]);  \
        *(f16x8*)&T[4 + arr][n][slot * 8] = fb.v; }

    // ---- tile 1: full-K MFMA (B2 loads draining underneath) ----
    f32x4 a1R[2] = {}, a1A[2] = {}, a1B[2] = {};
    __builtin_amdgcn_s_setprio(1);
    LOAD_A(0); STEP_B(2, 0, 0, a1R, a1A, a1B); STEP_B(2, 0, 1, a1R, a1A, a1B);
    LOAD_A(1); STEP_B(2, 1, 0, a1R, a1A, a1B); STEP_B(2, 1, 1, a1R, a1A, a1B);
    LOAD_A(2); STEP_B(2, 2, 0, a1R, a1A, a1B); STEP_B(2, 2, 1, a1R, a1A, a1B);
    LOAD_A(3); STEP_B(2, 3, 0, a1R, a1A, a1B); STEP_B(2, 3, 1, a1R, a1A, a1B);
    __builtin_amdgcn_s_setprio(0);

    // ---- tile1 stores interleaved with B2 cvt+write ----
    STORE_MS(tj1, 0, a1R, a1A, a1B);
    B2CVT(0); B2CVT(1);
    STORE_MS(tj1, 1, a1R, a1A, a1B);
    B2CVT(2); B2CVT(3);

    LBAR();   // B2 visible; tile1 stores still in flight

    // ---- tile 2: ks-outer (A-frags read once), ms-split tail ----
    f32x4 a2R[2] = {}, a2A[2] = {}, a2B[2] = {};
    __builtin_amdgcn_s_setprio(1);
    LOAD_A(0); STEP_B(4, 0, 0, a2R, a2A, a2B); STEP_B(4, 0, 1, a2R, a2A, a2B);
    LOAD_A(1); STEP_B(4, 1, 0, a2R, a2A, a2B); STEP_B(4, 1, 1, a2R, a2A, a2B);
    LOAD_A(2); STEP_B(4, 2, 0, a2R, a2A, a2B); STEP_B(4, 2, 1, a2R, a2A, a2B);
    LOAD_A(3); STEP_B(4, 3, 0, a2R, a2A, a2B);
    __builtin_amdgcn_s_setprio(0);
    STORE_MS(tj2, 0, a2R, a2A, a2B);   // drain starts while ms=1 finishes
    __builtin_amdgcn_s_setprio(1);
    STEP_B(4, 3, 1, a2R, a2A, a2B);
    __builtin_amdgcn_s_setprio(0);
    STORE_MS(tj2, 1, a2R, a2A, a2B);
}

extern "C" void kernel_launch(void* const* d_in, const int* in_sizes, int n_in,
                              void* d_out, int out_size, void* d_ws, size_t ws_size,
                              hipStream_t stream) {
    const float* R = (const float*)d_in[0];
    const float* I = (const float*)d_in[1];
    const float* W = (const float*)d_in[2];
    float* Or = (float*)d_out;
    float* Oi = (float*)d_out + (size_t)B * N * N;

    ComplexMixture_71313636983193_kernel<<<dim3(256), dim3(512), 0, stream>>>(
        R, I, W, Or, Oi);
}